// Round 1
// baseline (143.504 us; speedup 1.0000x reference)
//
#include <hip/hip_runtime.h>
#include <stdint.h>

// minerva2: echo = (F̂ Ê^T)^3 @ V, intensity = rowsum((F̂ Ê^T)^3)
// Fused flash-style bf16 MFMA implementation.

typedef unsigned short u16;
typedef __bf16 bf16x8 __attribute__((ext_vector_type(8)));
typedef float f32x4 __attribute__((ext_vector_type(4)));
typedef unsigned short u16x4 __attribute__((ext_vector_type(4)));

#define NQ 8192
#define ND 16384
#define NH 256
#define NC 28
#define BM 128
#define BD 128
#define DCHUNK 2048
#define NDT 16       // D-tiles per chunk
#define NSLOT 16     // partial slots = 8 chunks * 2 wc

__device__ __forceinline__ u16 f2bf(float f) {
  unsigned u = __builtin_bit_cast(unsigned, f);
  u += 0x7fffu + ((u >> 16) & 1u);   // RNE
  return (u16)(u >> 16);
}

__device__ __forceinline__ void gload16(const void* g, void* l) {
  // async global->LDS, 16B/lane; LDS dest = wave-uniform base + lane*16
  __builtin_amdgcn_global_load_lds(
      (__attribute__((address_space(1))) void*)g,
      (__attribute__((address_space(3))) void*)l, 16, 0, 0);
}

// ---------------- normalize rows of [rows][256] f32 -> bf16 ----------------
__global__ __launch_bounds__(256) void norm_kernel(const float* __restrict__ in,
                                                   u16* __restrict__ out, int rows) {
  const int wid = threadIdx.x >> 6, lane = threadIdx.x & 63;
  const int row = blockIdx.x * 4 + wid;
  if (row >= rows) return;
  const float4* p = (const float4*)(in + (size_t)row * NH);
  float4 v = p[lane];
  float ss = v.x * v.x + v.y * v.y + v.z * v.z + v.w * v.w;
#pragma unroll
  for (int m = 1; m <= 32; m <<= 1) ss += __shfl_xor(ss, m, 64);
  const float sc = 1.0f / fmaxf(sqrtf(ss), 1e-12f);  // matches F.normalize eps
  u16x4 o;
  o.x = f2bf(v.x * sc); o.y = f2bf(v.y * sc);
  o.z = f2bf(v.z * sc); o.w = f2bf(v.w * sc);
  *(u16x4*)(out + (size_t)row * NH + lane * 4) = o;
}

// ---------------- V [16384][28] f32 -> Vt [32][16384] bf16 (pad cols) ------
__global__ __launch_bounds__(256) void vt_kernel(const float* __restrict__ V,
                                                 u16* __restrict__ Vt) {
  const int d = blockIdx.x * 256 + threadIdx.x;  // 16384
#pragma unroll
  for (int c = 0; c < NC; ++c) Vt[(size_t)c * ND + d] = f2bf(V[(size_t)d * NC + c]);
#pragma unroll
  for (int c = NC; c < 32; ++c) Vt[(size_t)c * ND + d] = 0;
}

// ---------------- fused main kernel ----------------------------------------
// grid 512 = 64 ntiles * 8 dchunks; 256 threads = 4 waves (2x2 over 128x128 S)
__global__ __launch_bounds__(256, 2) void fused_kernel(
    const u16* __restrict__ Qn, const u16* __restrict__ Kn,
    const u16* __restrict__ Vt, float* __restrict__ ep, float* __restrict__ ip) {
  // LDS: Qbuf0 [0,16K) Qbuf1 [16K,32K) Kbuf0 [32K,48K) Kbuf1 [48K,64K)
  // a_lds aliases [0,32K): per-wave 8KB region (safe: barriers separate phases)
  __shared__ alignas(16) char smem[65536];
  const int tid = threadIdx.x;
  const int wid = tid >> 6;
  const int lane = tid & 63;
  const int l16 = lane & 15;
  const int lg = lane >> 4;
  const int wr = wid >> 1;
  const int wc = wid & 1;
  const int ntile = blockIdx.x & 63;
  const int dch = blockIdx.x >> 6;
  const int qbase = ntile * BM;

  f32x4 eacc[4][2];
  float iacc[4][4];
#pragma unroll
  for (int mb = 0; mb < 4; ++mb) {
#pragma unroll
    for (int cn = 0; cn < 2; ++cn) eacc[mb][cn] = f32x4{0.f, 0.f, 0.f, 0.f};
#pragma unroll
    for (int r = 0; r < 4; ++r) iacc[mb][r] = 0.f;
  }

  f32x4 sacc[4][4];

  // stage one 64-wide H-slab of Q-tile and K-tile into buf (row-major [128][64])
  auto stage = [&](int buf, int h0, int dbase) {
#pragma unroll
    for (int r = 0; r < 4; ++r) {
      const int row = r * 32 + (tid >> 3);
      const int c8 = tid & 7;
      gload16(Qn + (size_t)(qbase + row) * NH + h0 + c8 * 8,
              smem + buf * 16384 + r * 4096 + wid * 1024);
      gload16(Kn + (size_t)(dbase + row) * NH + h0 + c8 * 8,
              smem + 32768 + buf * 16384 + r * 4096 + wid * 1024);
    }
  };

  auto compute_s = [&](int buf) {
    const char* qb = smem + buf * 16384;
    const char* kb = smem + 32768 + buf * 16384;
#pragma unroll
    for (int k2 = 0; k2 < 2; ++k2) {
      bf16x8 A[4], B[4];
#pragma unroll
      for (int mb = 0; mb < 4; ++mb)
        A[mb] = *(const bf16x8*)(qb + (wr * 64 + mb * 16 + l16) * 128 + k2 * 64 + lg * 16);
#pragma unroll
      for (int nb = 0; nb < 4; ++nb)
        B[nb] = *(const bf16x8*)(kb + (wc * 64 + nb * 16 + l16) * 128 + k2 * 64 + lg * 16);
#pragma unroll
      for (int mb = 0; mb < 4; ++mb)
#pragma unroll
        for (int nb = 0; nb < 4; ++nb)
          sacc[mb][nb] = __builtin_amdgcn_mfma_f32_16x16x32_bf16(
              A[mb], B[nb], sacc[mb][nb], 0, 0, 0);
    }
  };

  for (int t = 0; t < NDT; ++t) {
    const int dbase = dch * DCHUNK + t * BD;
#pragma unroll
    for (int mb = 0; mb < 4; ++mb)
#pragma unroll
      for (int nb = 0; nb < 4; ++nb) sacc[mb][nb] = f32x4{0.f, 0.f, 0.f, 0.f};

    stage(0, 0, dbase);
    __syncthreads();
#pragma unroll
    for (int ks = 0; ks < 4; ++ks) {
      if (ks < 3) stage((ks + 1) & 1, (ks + 1) * 64, dbase);
      compute_s(ks & 1);
      __syncthreads();
    }

    // PV B-frags from global Vt (L2-resident): B[32d x 16c], lane: c=l16, d=lg*8+i
    bf16x8 vB[2][2];
    const int dglob = dbase + wc * 64;
#pragma unroll
    for (int dk = 0; dk < 2; ++dk)
#pragma unroll
      for (int cn = 0; cn < 2; ++cn)
        vB[dk][cn] = *(const bf16x8*)(Vt + (size_t)(cn * 16 + l16) * ND +
                                      dglob + dk * 32 + lg * 8);

    // cube (fp32), accumulate intensity, stash bf16 a into swizzled LDS
    char* aw = smem + wid * 8192;  // per-wave private [64][64] bf16, 16B-chunk XOR swizzle
#pragma unroll
    for (int mb = 0; mb < 4; ++mb) {
#pragma unroll
      for (int nb = 0; nb < 4; ++nb) {
        f32x4 s = sacc[mb][nb];
        f32x4 a3 = s * s * s;
#pragma unroll
        for (int r = 0; r < 4; ++r) {
          iacc[mb][r] += a3[r];
          const int row = mb * 16 + lg * 4 + r;   // C/D layout: row=(lane>>4)*4+reg
          const int col = nb * 16 + l16;          //              col=lane&15
          *(u16*)(aw + row * 128 + (((col >> 3) ^ (row & 7)) << 4) + (col & 7) * 2) =
              f2bf(a3[r]);
        }
      }
    }

    // PV: echo[q, c] += a[q, d] * V[d, c]
#pragma unroll
    for (int mb = 0; mb < 4; ++mb) {
#pragma unroll
      for (int dk = 0; dk < 2; ++dk) {
        const int row = mb * 16 + l16;
        const bf16x8 aA =
            *(const bf16x8*)(aw + row * 128 + (((dk * 4 + lg) ^ (row & 7)) << 4));
#pragma unroll
        for (int cn = 0; cn < 2; ++cn)
          eacc[mb][cn] = __builtin_amdgcn_mfma_f32_16x16x32_bf16(
              aA, vB[dk][cn], eacc[mb][cn], 0, 0, 0);
      }
    }
    __syncthreads();  // a_lds reads done before next tile's staging overwrites
  }

  // ---- epilogue: write partials (slot = dch*2 + wc) ----
  const int slot = dch * 2 + wc;
#pragma unroll
  for (int mb = 0; mb < 4; ++mb) {
#pragma unroll
    for (int r = 0; r < 4; ++r) {
      float v = iacc[mb][r];
      v += __shfl_xor(v, 1, 64);
      v += __shfl_xor(v, 2, 64);
      v += __shfl_xor(v, 4, 64);
      v += __shfl_xor(v, 8, 64);
      if (l16 == 0) {
        const int row = qbase + wr * 64 + mb * 16 + lg * 4 + r;
        ip[(size_t)slot * NQ + row] = v;
      }
    }
  }
#pragma unroll
  for (int mb = 0; mb < 4; ++mb)
#pragma unroll
    for (int cn = 0; cn < 2; ++cn)
#pragma unroll
      for (int r = 0; r < 4; ++r) {
        const int row = qbase + wr * 64 + mb * 16 + lg * 4 + r;
        const int col = cn * 16 + l16;
        ep[((size_t)slot * NQ + row) * 32 + col] = eacc[mb][cn][r];
      }
}

// ---------------- reduce 16 partial slots -> d_out -------------------------
__global__ __launch_bounds__(256) void reduce_kernel(const float* __restrict__ ep,
                                                     const float* __restrict__ ip,
                                                     float* __restrict__ out) {
  const int g = blockIdx.x * 256 + threadIdx.x;  // 8192*32
  const int q = g >> 5, c = g & 31;
  if (c < NC) {
    float s = 0.f;
#pragma unroll
    for (int k = 0; k < NSLOT; ++k) s += ep[((size_t)k * NQ + q) * 32 + c];
    out[(size_t)q * NC + c] = s;
  } else if (c == NC) {
    float s = 0.f;
#pragma unroll
    for (int k = 0; k < NSLOT; ++k) s += ip[(size_t)k * NQ + q];
    out[(size_t)NQ * NC + q] = s;
  }
}

extern "C" void kernel_launch(void* const* d_in, const int* in_sizes, int n_in,
                              void* d_out, int out_size, void* d_ws, size_t ws_size,
                              hipStream_t stream) {
  const float* feat = (const float*)d_in[0];  // [8192][256]
  const float* exf  = (const float*)d_in[1];  // [16384][256]
  const float* exc  = (const float*)d_in[2];  // [16384][28]
  float* out = (float*)d_out;
  char* ws = (char*)d_ws;
  // ws layout (bytes): qn 4MB | kn 8MB | vt 1MB | ep 16MB | ip 512KB  (~29.5MB)
  u16* qn = (u16*)ws;
  u16* kn = (u16*)(ws + 4194304);
  u16* vt = (u16*)(ws + 12582912);
  float* ep = (float*)(ws + 13631488);
  float* ip = (float*)(ws + 30408704);

  norm_kernel<<<dim3(NQ / 4), dim3(256), 0, stream>>>(feat, qn, NQ);
  norm_kernel<<<dim3(ND / 4), dim3(256), 0, stream>>>(exf, kn, ND);
  vt_kernel<<<dim3(ND / 256), dim3(256), 0, stream>>>(exc, vt);
  fused_kernel<<<dim3(512), dim3(256), 0, stream>>>(qn, kn, vt, ep, ip);
  reduce_kernel<<<dim3(NQ * 32 / 256), dim3(256), 0, stream>>>(ep, ip, out);
}